// Round 3
// baseline (2160.749 us; speedup 1.0000x reference)
//
#include <hip/hip_runtime.h>
#include <hip/hip_bf16.h>

typedef short s8v __attribute__((ext_vector_type(8)));
typedef float f4 __attribute__((ext_vector_type(4)));
typedef unsigned short us8 __attribute__((ext_vector_type(8)));

#define NIMG 16
#define HH 64
#define HL 128
#define K1 2304

// ------------------------------------------------------------------
// prep: weights -> [m=512][k=2304] bf16 hi/lo, k = (dy*3+dx)*256 + c
__global__ void prep_weights(const float* __restrict__ w_e1, const float* __restrict__ w_c1,
                             unsigned short* __restrict__ Ah, unsigned short* __restrict__ Al) {
  int gid = blockIdx.x * 256 + threadIdx.x;
  if (gid >= 512 * 2304) return;
  int m = gid / 2304, k = gid % 2304;
  int dydx = k >> 8, c = k & 255;
  int dy = dydx / 3, dx = dydx - 3 * dy;
  const float* w = (m < 256) ? w_e1 : w_c1;
  int mm = m & 255;
  float v = w[((mm * 256 + c) * 3 + dy) * 3 + dx];
  __hip_bfloat16 h = __float2bfloat16(v);
  float hv = __bfloat162float(h);
  __hip_bfloat16 lo = __float2bfloat16(v - hv);
  Ah[gid] = *(unsigned short*)&h;
  Al[gid] = *(unsigned short*)&lo;
}

__global__ void prep_bn(const float* g_e, const float* b_e, const float* m_e, const float* v_e,
                        const float* g_c, const float* b_c, const float* m_c, const float* v_c,
                        float* __restrict__ bnsc, float* __restrict__ bnsh) {
  int i = blockIdx.x * 256 + threadIdx.x;
  if (i >= 512) return;
  int c = i & 255;
  const float* g = (i < 256) ? g_e : g_c;
  const float* b = (i < 256) ? b_e : b_c;
  const float* mu = (i < 256) ? m_e : m_c;
  const float* vv = (i < 256) ? v_e : v_c;
  float sc = g[c] / sqrtf(vv[c] + 1e-5f);
  bnsc[i] = sc;
  bnsh[i] = b[c] - mu[c] * sc;
}

// ------------------------------------------------------------------
// x_high (NCHW f32) -> padded NHWC bf16 hi/lo  P[n][yy(66)][xx(66)][c(256)]
__global__ void pad_convert(const float* __restrict__ xh,
                            unsigned short* __restrict__ Ph, unsigned short* __restrict__ Pl) {
  __shared__ unsigned int L[64 * 130];
  int n = blockIdx.x >> 6, y = blockIdx.x & 63;
  int t = threadIdx.x;
  int x = t & 63, ch = t >> 6;
  for (int r = 0; r < 2; ++r) {
    __syncthreads();
    for (int i = 0; i < 32; ++i) {
      int cl = 4 * i + ch;
      float v = xh[(((size_t)n * 256 + r * 128 + cl) * 64 + y) * 64 + x];
      __hip_bfloat16 h = __float2bfloat16(v);
      float hv = __bfloat162float(h);
      __hip_bfloat16 lo = __float2bfloat16(v - hv);
      L[x * 130 + cl] = (((unsigned)*(unsigned short*)&h) << 16) | (*(unsigned short*)&lo);
    }
    __syncthreads();
    for (int j = 0; j < 4; ++j) {
      int id = j * 256 + t;
      int px = id >> 4, chk = id & 15;
      size_t base = ((((size_t)n * 66 + y + 1) * 66) + px + 1) * 256 + r * 128 + chk * 8;
      us8 hv8, lv8;
#pragma unroll
      for (int e = 0; e < 8; ++e) {
        unsigned u = L[px * 130 + chk * 8 + e];
        hv8[e] = (unsigned short)(u >> 16);
        lv8[e] = (unsigned short)(u & 0xffffu);
      }
      *(us8*)&Ph[base] = hv8;
      *(us8*)&Pl[base] = lv8;
    }
    __syncthreads();
  }
}

// ------------------------------------------------------------------
// conv1 as split-bf16 GEMM: D[m=512][pix=65536], K=2304, 3 passes.
// m97-style 128x128 tile, BK=64, 4 waves, global_load_lds(16B).
__global__ __launch_bounds__(256) void conv1_gemm(
    const unsigned short* __restrict__ Ah, const unsigned short* __restrict__ Al,
    const unsigned short* __restrict__ Ph, const unsigned short* __restrict__ Pl,
    const float* __restrict__ bnsc, const float* __restrict__ bnsh,
    float* __restrict__ act) {
  __shared__ unsigned short As[128 * 64];
  __shared__ unsigned short Bs[128 * 64];
  int bid = blockIdx.x;
  int sw = ((bid & 7) << 8) | (bid >> 3);  // 2048 = 8 XCD * 256, bijective
  int mt = sw & 3, nt = sw >> 2;
  int m0 = mt << 7;
  int pix0 = nt << 7;
  int img = pix0 >> 12;
  int y0 = (pix0 & 4095) >> 6;
  int t = threadIdx.x, w = t >> 6, l = t & 63;
  int lc = l & 7;
  int lm = l & 15, lk = (l >> 4) << 3;
  int wr = w >> 1, wc = w & 1;
  f4 acc[4][4];
#pragma unroll
  for (int mi = 0; mi < 4; ++mi)
#pragma unroll
    for (int ni = 0; ni < 4; ++ni) acc[mi][ni] = (f4){0.f, 0.f, 0.f, 0.f};

  for (int kk = 0; kk < 108; ++kk) {
    const unsigned short* Aq = (kk < 72) ? Ah : Al;
    const unsigned short* Bq = (kk < 36 || kk >= 72) ? Ph : Pl;
    int sub = kk - (kk >= 72 ? 72 : (kk >= 36 ? 36 : 0));
    int kg = sub << 6;
    int dydx = kg >> 8, c0 = kg & 255;
    int dy = dydx / 3, dx = dydx - 3 * dy;
    __syncthreads();
#pragma unroll
    for (int i = 0; i < 4; ++i) {
      int row = (w << 5) + (i << 3) + (l >> 3);
      const unsigned short* srcA = Aq + (size_t)(m0 + row) * 2304 + kg + (lc << 3);
      __builtin_amdgcn_global_load_lds(
          (const __attribute__((address_space(1))) unsigned int*)srcA,
          (__attribute__((address_space(3))) unsigned int*)&As[row * 64 + (lc << 3)], 16, 0, 0);
      int py = y0 + (row >> 6), px = row & 63;
      const unsigned short* srcB =
          Bq + ((size_t)((img * 66 + py + dy) * 66) + px + dx) * 256 + c0 + (lc << 3);
      __builtin_amdgcn_global_load_lds(
          (const __attribute__((address_space(1))) unsigned int*)srcB,
          (__attribute__((address_space(3))) unsigned int*)&Bs[row * 64 + (lc << 3)], 16, 0, 0);
    }
    __syncthreads();
#pragma unroll
    for (int ks = 0; ks < 2; ++ks) {
      s8v aF[4], bF[4];
#pragma unroll
      for (int mi = 0; mi < 4; ++mi)
        aF[mi] = *(const s8v*)&As[((wr << 6) + (mi << 4) + lm) * 64 + (ks << 5) + lk];
#pragma unroll
      for (int ni = 0; ni < 4; ++ni)
        bF[ni] = *(const s8v*)&Bs[((wc << 6) + (ni << 4) + lm) * 64 + (ks << 5) + lk];
#pragma unroll
      for (int mi = 0; mi < 4; ++mi)
#pragma unroll
        for (int ni = 0; ni < 4; ++ni)
          acc[mi][ni] = __builtin_amdgcn_mfma_f32_16x16x32_bf16(aF[mi], bF[ni], acc[mi][ni], 0, 0, 0);
    }
  }
  // epilogue: BN + ReLU, act[img][m][pix] NCHW f32
  int l4 = (l >> 4) << 2;
#pragma unroll
  for (int mi = 0; mi < 4; ++mi) {
    int mb = m0 + (wr << 6) + (mi << 4) + l4;
    float sc[4], sh[4];
#pragma unroll
    for (int j = 0; j < 4; ++j) { sc[j] = bnsc[mb + j]; sh[j] = bnsh[mb + j]; }
#pragma unroll
    for (int ni = 0; ni < 4; ++ni) {
      int pixl = (wc << 6) + (ni << 4) + lm;
      int pin = (pix0 & 4095) + pixl;
      size_t obase = ((size_t)img * 512 + mb) * 4096 + pin;
#pragma unroll
      for (int j = 0; j < 4; ++j) {
        float v = acc[mi][ni][j] * sc[j] + sh[j];
        act[obase + (size_t)j * 4096] = v > 0.f ? v : 0.f;
      }
    }
  }
}

// ------------------------------------------------------------------
// conv2: edge 3x3 (ch 0..255), corner 1x1 (ch 256..511)
__global__ void conv2_kernel(const float* __restrict__ act, const float* __restrict__ w_e2,
                             const float* __restrict__ w_c2, float* __restrict__ predE,
                             float* __restrict__ predC) {
  int gid = blockIdx.x * 256 + threadIdx.x;
  int branch = gid >> 16;
  int pid = gid & 65535;
  int n = pid >> 12, rem = pid & 4095, y = rem >> 6, x = rem & 63;
  float s = 0.f;
  if (branch == 0) {
    const float* a = act + (size_t)n * 512 * 4096;
    for (int c = 0; c < 256; ++c) {
      const float* ac = a + (size_t)c * 4096;
      const float* wk = w_e2 + c * 9;
#pragma unroll
      for (int dy = 0; dy < 3; ++dy) {
        int yy = y + dy - 1;
        if ((unsigned)yy >= 64u) continue;
#pragma unroll
        for (int dx = 0; dx < 3; ++dx) {
          int xx = x + dx - 1;
          if ((unsigned)xx >= 64u) continue;
          s += ac[yy * 64 + xx] * wk[dy * 3 + dx];
        }
      }
    }
    predE[pid] = s;
  } else {
    const float* a = act + ((size_t)n * 512 + 256) * 4096 + rem;
    for (int c = 0; c < 256; ++c) s += a[(size_t)c * 4096] * w_c2[c];
    predC[pid] = s;
  }
}

// ------------------------------------------------------------------
// top-128 of 4096 per (branch,n), radix-select; ties -> lowest index.
__global__ void topk_kernel(const float* __restrict__ predE, const float* __restrict__ predC,
                            int* __restrict__ idxAll, int* __restrict__ lowAll) {
  __shared__ unsigned hist[256];
  __shared__ unsigned sh_byte, sh_cum;
  __shared__ int eqList[4096];
  __shared__ int eqCnt, outCnt;
  int b = blockIdx.x;
  int branch = b >> 4, n = b & 15;
  const float* pred = (branch ? predC : predE) + n * 4096;
  int t = threadIdx.x;
  unsigned key[16];
#pragma unroll
  for (int i = 0; i < 16; ++i) {
    unsigned u = __float_as_uint(pred[i * 256 + t]);
    key[i] = (u & 0x80000000u) ? ~u : (u | 0x80000000u);
  }
  unsigned prefix = 0;
  int need = 128;
  for (int shift = 24; shift >= 0; shift -= 8) {
    hist[t] = 0;
    __syncthreads();
    unsigned himask = (shift == 24) ? 0u : (0xFFFFFFFFu << (shift + 8));
#pragma unroll
    for (int i = 0; i < 16; ++i) {
      if ((key[i] & himask) == (prefix & himask))
        atomicAdd(&hist[(key[i] >> shift) & 255], 1u);
    }
    __syncthreads();
    if (t == 0) {
      unsigned cum = 0;
      int v = 255;
      for (; v > 0; --v) {
        if (cum + hist[v] >= (unsigned)need) break;
        cum += hist[v];
      }
      sh_byte = (unsigned)v;
      sh_cum = cum;
    }
    __syncthreads();
    prefix |= (sh_byte << shift);
    need -= (int)sh_cum;
    __syncthreads();
  }
  if (t == 0) { eqCnt = 0; outCnt = 0; }
  __syncthreads();
  int* idxOut = idxAll + b * 128;
  int* lowOut = lowAll + b * 128;
#pragma unroll
  for (int i = 0; i < 16; ++i) {
    int e = i * 256 + t;
    if (key[i] > prefix) {
      int s = atomicAdd(&outCnt, 1);
      idxOut[s] = e;
    } else if (key[i] == prefix) {
      int s = atomicAdd(&eqCnt, 1);
      if (s < 4096) eqList[s] = e;
    }
  }
  __syncthreads();
  int needEq = need;
#pragma unroll
  for (int i = 0; i < 16; ++i) {
    int e = i * 256 + t;
    if (key[i] == prefix) {
      int rank = 0;
      int E = eqCnt;
      for (int j = 0; j < E; ++j) rank += (eqList[j] < e) ? 1 : 0;
      if (rank < needEq) {
        int s = atomicAdd(&outCnt, 1);
        idxOut[s] = e;
      }
    }
  }
  __syncthreads();
  if (t < 128) {
    int e = idxOut[t];
    lowOut[t] = ((e & 63) << 1) + ((e >> 6) << 8);  // 2*x + 2*y*128
  }
}

// ------------------------------------------------------------------
// gathers: Hf[c][p] = x_high at point; Lf = exact 2x2 avg of x_low
// 256 blocks: blockIdx = b*8 + slice; each block covers 32 channels.
__global__ void gather_kernel(const float* __restrict__ xh, const float* __restrict__ xl,
                              const int* __restrict__ idxAll, float* __restrict__ HfAll,
                              float* __restrict__ LfAll) {
  int b = blockIdx.x >> 3;
  int slice = blockIdx.x & 7;
  int n = b & 15;
  int t = threadIdx.x;
  int p = t & 127, half = t >> 7;
  int e = idxAll[b * 128 + p];
  int xs = e & 63, ys = e >> 6;
  float* Hf = HfAll + (size_t)b * 32768;
  float* Lf = LfAll + (size_t)b * 32768;
  const float* xhn = xh + (size_t)n * 256 * 4096;
  const float* xln = xl + (size_t)n * 256 * 16384;
  int c0 = slice * 32 + half * 16;
  for (int ci = 0; ci < 16; ++ci) {
    int c = c0 + ci;
    Hf[c * 128 + p] = xhn[(size_t)c * 4096 + ys * 64 + xs];
    const float* q = xln + (size_t)c * 16384 + (ys * 2) * 128 + xs * 2;
    Lf[c * 128 + p] = ((q[0] * 0.25f + q[1] * 0.25f) + q[128] * 0.25f) + q[129] * 0.25f;
  }
}

// ------------------------------------------------------------------
__global__ void copy_low(const f4* __restrict__ src, f4* __restrict__ dst) {
  size_t i = (size_t)blockIdx.x * 256 + threadIdx.x;
  const size_t tot = (size_t)16 * 256 * 128 * 128 / 4;
  for (; i < tot; i += (size_t)2048 * 256) dst[i] = src[i];
}

// ------------------------------------------------------------------
// affinity softmax + fusion + scatter, one block per image
__global__ __launch_bounds__(256) void fuse_scatter(
    const float* __restrict__ HfAll, const float* __restrict__ LfAll,
    const int* __restrict__ lowAll, float* __restrict__ out0, int branch) {
  __shared__ float Hc[32 * 128];
  __shared__ float Lc[32 * 128];
  int n = blockIdx.x;
  int b = branch * 16 + n;
  const float* Hf = HfAll + (size_t)b * 32768;
  const float* Lf = LfAll + (size_t)b * 32768;
  const int* low = lowAll + b * 128;
  int t = threadIdx.x;
  int q = t >> 1, p0 = (t & 1) << 6;
  float a[64];
#pragma unroll
  for (int j = 0; j < 64; ++j) a[j] = 0.f;
  for (int c0 = 0; c0 < 256; c0 += 32) {
    __syncthreads();
    for (int i = t; i < 4096; i += 256) {
      Hc[i] = Hf[c0 * 128 + i];
      Lc[i] = Lf[c0 * 128 + i];
    }
    __syncthreads();
    for (int cc = 0; cc < 32; ++cc) {
      float lv = Lc[cc * 128 + q];
      const float* hr = &Hc[cc * 128 + p0];
#pragma unroll
      for (int j = 0; j < 64; ++j) a[j] += hr[j] * lv;
    }
  }
  float mx = a[0];
#pragma unroll
  for (int j = 1; j < 64; ++j) mx = fmaxf(mx, a[j]);
  mx = fmaxf(mx, __shfl_xor(mx, 1));
  float sum = 0.f;
#pragma unroll
  for (int j = 0; j < 64; ++j) {
    a[j] = expf(a[j] - mx);
    sum += a[j];
  }
  sum += __shfl_xor(sum, 1);
  float inv = 1.f / sum;
#pragma unroll
  for (int j = 0; j < 64; ++j) a[j] *= inv;
  int myLow = low[q];
  size_t outBase = (size_t)n * 256 * 16384;
  for (int c0 = 0; c0 < 256; c0 += 32) {
    __syncthreads();
    for (int i = t; i < 4096; i += 256) Hc[i] = Hf[c0 * 128 + i];
    __syncthreads();
    for (int cc = 0; cc < 32; ++cc) {
      const float* hr = &Hc[cc * 128 + p0];
      float s = 0.f;
#pragma unroll
      for (int j = 0; j < 64; ++j) s += a[j] * hr[j];
      s += __shfl_xor(s, 1);
      if ((t & 1) == 0) {
        int c = c0 + cc;
        out0[outBase + (size_t)c * 16384 + myLow] = s + Lf[c * 128 + q];
      }
    }
  }
}

// ------------------------------------------------------------------
extern "C" void kernel_launch(void* const* d_in, const int* in_sizes, int n_in,
                              void* d_out, int out_size, void* d_ws, size_t ws_size,
                              hipStream_t stream) {
  const float* xh = (const float*)d_in[0];
  const float* xl = (const float*)d_in[1];
  const float* w_e1 = (const float*)d_in[2];
  const float* g_e = (const float*)d_in[3];
  const float* b_e = (const float*)d_in[4];
  const float* m_e = (const float*)d_in[5];
  const float* v_e = (const float*)d_in[6];
  const float* w_e2 = (const float*)d_in[7];
  const float* w_c1 = (const float*)d_in[8];
  const float* g_c = (const float*)d_in[9];
  const float* b_c = (const float*)d_in[10];
  const float* m_c = (const float*)d_in[11];
  const float* v_c = (const float*)d_in[12];
  const float* w_c2 = (const float*)d_in[13];

  char* ws = (char*)d_ws;
  const size_t SP = (size_t)16 * 66 * 66 * 256 * 2;  // 35,684,352 bytes
  const size_t SA = (size_t)512 * 2304 * 2;          //  2,359,296 bytes
  unsigned short* Ph = (unsigned short*)ws;
  unsigned short* Pl = (unsigned short*)(ws + SP);
  unsigned short* Ah = (unsigned short*)(ws + 2 * SP);
  unsigned short* Al = (unsigned short*)(ws + 2 * SP + SA);
  float* bnsc = (float*)(ws + 2 * SP + 2 * SA);
  float* bnsh = bnsc + 512;
  int* idxAll = (int*)(ws + 2 * SP + 2 * SA + 8192);           // [2][16][128]
  int* lowAll = idxAll + 4096;                                  // [2][16][128]
  float* HfAll = (float*)(ws + 2 * SP + 2 * SA + 8192 + 65536); // [2][16][256][128]
  float* LfAll = HfAll + (size_t)2 * 16 * 256 * 128;

  float* out0 = (float*)d_out;
  float* predE = out0 + (size_t)16 * 256 * 128 * 128;
  float* predC = predE + 65536;
  float* act = out0;  // reuse out0 region as conv1-activation scratch

  hipMemsetAsync(Ph, 0, 2 * SP, stream);  // zero padded borders
  prep_weights<<<4608, 256, 0, stream>>>(w_e1, w_c1, Ah, Al);
  prep_bn<<<2, 256, 0, stream>>>(g_e, b_e, m_e, v_e, g_c, b_c, m_c, v_c, bnsc, bnsh);
  pad_convert<<<1024, 256, 0, stream>>>(xh, Ph, Pl);
  conv1_gemm<<<2048, 256, 0, stream>>>(Ah, Al, Ph, Pl, bnsc, bnsh, act);
  conv2_kernel<<<512, 256, 0, stream>>>(act, w_e2, w_c2, predE, predC);
  topk_kernel<<<32, 256, 0, stream>>>(predE, predC, idxAll, lowAll);
  gather_kernel<<<256, 256, 0, stream>>>(xh, xl, idxAll, HfAll, LfAll);
  copy_low<<<2048, 256, 0, stream>>>((const f4*)xl, (f4*)out0);
  fuse_scatter<<<16, 256, 0, stream>>>(HfAll, LfAll, lowAll, out0, 0);
  fuse_scatter<<<16, 256, 0, stream>>>(HfAll, LfAll, lowAll, out0, 1);
}